// Round 6
// baseline (329.672 us; speedup 1.0000x reference)
//
#include <hip/hip_runtime.h>
#include <hip/hip_bf16.h>
#include <stdint.h>

#define DEV __device__ __forceinline__

typedef __attribute__((ext_vector_type(8))) short short8;    // 8 bf16 (MFMA A/B frag)
typedef __attribute__((ext_vector_type(4))) float floatx4;   // MFMA C/D frag

constexpr int TM  = 128;    // rows per block (8 waves)
constexpr int NB  = 131072; // batch
constexpr int AST = 264;    // act row stride (bf16 elems); 264*2B = 16B-multiple

// ---- packed bf16 weight layout in d_ws (element offsets) ----
constexpr int OFF_W1 = 0;        // 4w x 7kc x 4ct x 512   (K=224: 199 state + td + BIAS@200)
constexpr int OFF_W2 = 57344;    // 4w x 8 x 4 x 512       (K=256, N=256)
constexpr int OFF_W3 = 122880;   // 4w x 8 x 2 x 512       (K=256, N=128)
constexpr int OFF_WH = 155648;   // 4h x 4 x 4 x 512       (K=128, N=64; h=0..2 adv, h=3 value)
constexpr int OFF_WA2= 188416;   // 3h x 2 x 2 x 512       (K=64,  N=32)
constexpr int NWQ    = 194560;

constexpr int C_B1=0, C_G1=256, C_BE1=512, C_B2=768, C_G2=1024, C_BE2=1280,
  C_B3=1536, C_G3=1664, C_BE3=1792, C_BV1=1920, C_GV=1984, C_BEV=2048,
  C_WV2=2112, C_BV2=2176, C_BA1=2177, C_GA=2369, C_BEA=2561, C_BA2=2753;
constexpr int NCONST=2849;

struct Ptrs {
  const float *state,*td,*W1,*b1,*g1,*be1,*W2,*b2,*g2,*be2,*W3,*b3,*g3,*be3,
    *Wv1,*bv1,*gv,*bev,*Wv2,*bv2,*Wa1,*ba1,*ga,*bea,*Wa2,*ba2;
  const int *et;
};

DEV unsigned short f2bf(float x){
  uint32_t u = __float_as_uint(x);
  u += 0x7fffu + ((u>>16)&1u);
  return (unsigned short)(u>>16);
}
DEV uint32_t f2bf_pk(float a, float b){
  float2 f2; f2.x=a; f2.y=b;
  __hip_bfloat162 h = __float22bfloat162_rn(f2);
  union { __hip_bfloat162 h; uint32_t u; } cv; cv.h = h;
  return cv.u;
}

// =====================================================================
// prep. k-permutations invert producers' packed act layouts:
//   L1/L2 lnWrite (CT=4, 64-col block): p = 4*(c&15) + ((c>>4)&3)
//   L3 f-write (CT=8, 128 cols):        p = 8*(c&15) + (c>>4)
//   head ha-write (CT=4, 64 cols):      p = 4*(c&15) + (c>>4)
// =====================================================================
__global__ void prep_kernel(Ptrs p, unsigned short* __restrict__ wq, float* __restrict__ cq){
  int idx = blockIdx.x*256 + threadIdx.x;
  if (idx < NWQ) {
    float v = 0.f;
    if (idx < OFF_W2) {                       // W1 (+bias row at k=200), k unpermuted
      int e = idx, w = e/14336, r = e%14336;
      int kc = r>>11, ct=(r>>9)&3, l=(r>>3)&63, j=r&7;
      int n = w*64 + ct*16 + (l&15);
      int k = kc*32 + (l>>4)*8 + j;
      if (k < 200) v = p.W1[k*256 + n];
      else if (k == 200) v = p.b1[n];
    } else if (idx < OFF_W3) {                // W2: producer = L1 lnWrite (CT=4)
      int e = idx-OFF_W2, w=e>>14, r=e&16383;
      int kc=r>>11, ct=(r>>9)&3, l=(r>>3)&63, j=r&7;
      int n = w*64 + ct*16 + (l&15);
      int k = kc*32 + (l>>4)*8 + j;
      int c = (k & ~63) + 16*(k&3) + ((k&63)>>2);
      v = p.W2[c*256 + n];
    } else if (idx < OFF_WH) {                // W3: producer = L2 lnWrite (CT=4)
      int e = idx-OFF_W3, w=e>>13, r=e&8191;
      int kc=r>>10, ct=(r>>9)&1, l=(r>>3)&63, j=r&7;
      int n = w*32 + ct*16 + (l&15);
      int k = kc*32 + (l>>4)*8 + j;
      int c = (k & ~63) + 16*(k&3) + ((k&63)>>2);
      v = p.W3[c*128 + n];
    } else if (idx < OFF_WA2) {               // Wv1/Wa1: producer = L3 f-write (CT=8, 128 cols)
      int e = idx-OFF_WH, h=e>>13, r=e&8191;
      int kc=r>>11, ct=(r>>9)&3, l=(r>>3)&63, j=r&7;
      int n = ct*16 + (l&15);
      int k = kc*32 + (l>>4)*8 + j;          // k in 0..127
      int c = 16*(k&7) + (k>>3);
      v = (h<3) ? p.Wa1[h*8192 + c*64 + n] : p.Wv1[c*64 + n];
    } else {                                  // Wa2: producer = head ha-write (CT=4, 64 cols)
      int e = idx-OFF_WA2, h=e>>11, r=e&2047;
      int kc=r>>10, ct=(r>>9)&1, l=(r>>3)&63, j=r&7;
      int n = ct*16 + (l&15);
      int k = kc*32 + (l>>4)*8 + j;          // k in 0..63
      int c = 16*(k&3) + (k>>2);
      v = p.Wa2[h*2048 + c*32 + n];
    }
    wq[idx] = f2bf(v);
  } else if (idx < NWQ + NCONST) {
    int ci = idx - NWQ;
    const float* src; int off;
    if      (ci < 256)  { src=p.b1;  off=ci; }
    else if (ci < 512)  { src=p.g1;  off=ci-256; }
    else if (ci < 768)  { src=p.be1; off=ci-512; }
    else if (ci < 1024) { src=p.b2;  off=ci-768; }
    else if (ci < 1280) { src=p.g2;  off=ci-1024; }
    else if (ci < 1536) { src=p.be2; off=ci-1280; }
    else if (ci < 1664) { src=p.b3;  off=ci-1536; }
    else if (ci < 1792) { src=p.g3;  off=ci-1664; }
    else if (ci < 1920) { src=p.be3; off=ci-1792; }
    else if (ci < 1984) { src=p.bv1; off=ci-1920; }
    else if (ci < 2048) { src=p.gv;  off=ci-1984; }
    else if (ci < 2112) { src=p.bev; off=ci-2048; }
    else if (ci < 2176) { src=p.Wv2; off=ci-2112; }
    else if (ci < 2177) { src=p.bv2; off=ci-2176; }
    else if (ci < 2369) { src=p.ba1; off=ci-2177; }
    else if (ci < 2561) { src=p.ga;  off=ci-2369; }
    else if (ci < 2753) { src=p.bea; off=ci-2561; }
    else                { src=p.ba2; off=ci-2753; }
    cq[ci] = src[off];
  }
}

// =====================================================================
// device helpers — B loads stay IN the kc loop (no big register arrays)
// =====================================================================
DEV void zeroAcc44(floatx4 (&acc)[4][4]){
  const floatx4 z = {0.f,0.f,0.f,0.f};
  #pragma unroll
  for (int rt=0;rt<4;rt++)
    #pragma unroll
    for (int ct=0;ct<4;ct++) acc[rt][ct]=z;
}

template<int KC>
DEV void runGemm44(floatx4 (&acc)[4][4], const unsigned short* __restrict__ wsrc,
                   const unsigned short* aBase, int lane){
  #pragma unroll
  for (int kc=0;kc<KC;kc++){
    short8 b[4];
    #pragma unroll
    for (int ct=0;ct<4;ct++)
      b[ct] = *(const short8*)(wsrc + kc*2048 + ct*512 + lane*8);
    short8 a[4];
    #pragma unroll
    for (int rt=0;rt<4;rt++)
      a[rt] = *(const short8*)(aBase + rt*16*AST + kc*32);
    #pragma unroll
    for (int rt=0;rt<4;rt++)
      #pragma unroll
      for (int ct=0;ct<4;ct++)
        acc[rt][ct] = __builtin_amdgcn_mfma_f32_16x16x32_bf16(a[rt], b[ct], acc[rt][ct], 0,0,0);
  }
}

// bias + per-row (s,ss) partials over this wave's 64 cols -> LDS atomics
template<bool BIAS>
DEV void statsAtomic(const floatx4 (&acc)[4][4], const float* __restrict__ cq, int bo, int colBase,
                     int rowBase, float* sbuf, float* ssbuf, int ln, int q, float (&bias)[4]){
  #pragma unroll
  for (int ct=0;ct<4;ct++) bias[ct] = BIAS ? cq[bo+colBase+ct*16+ln] : 0.f;
  #pragma unroll
  for (int rt=0;rt<4;rt++){
    float s[4]={0,0,0,0}, ss[4]={0,0,0,0};
    #pragma unroll
    for (int ct=0;ct<4;ct++){
      #pragma unroll
      for (int r=0;r<4;r++){
        float v=acc[rt][ct][r]+bias[ct];
        s[r]+=v; ss[r]+=v*v;
      }
    }
    #pragma unroll
    for (int r=0;r<4;r++){
      #pragma unroll
      for (int d=1;d<16;d<<=1){ s[r]+=__shfl_xor(s[r],d); ss[r]+=__shfl_xor(ss[r],d); }
      if (ln==0){
        int row = rowBase + rt*16+q*4+r;
        atomicAdd(&sbuf[row],  s[r]);
        atomicAdd(&ssbuf[row], ss[r]);
      }
    }
  }
}

DEV void lnWrite44(const floatx4 (&acc)[4][4], const float* __restrict__ cq, int go, int beo,
                   int colBase, int rowBase, const float* sbuf, const float* ssbuf, float invN,
                   unsigned short* act_, int ln, int q, const float (&bias)[4]){
  float g[4], be[4];
  #pragma unroll
  for (int ct=0;ct<4;ct++){ g[ct]=cq[go+colBase+ct*16+ln]; be[ct]=cq[beo+colBase+ct*16+ln]; }
  #pragma unroll
  for (int rt=0;rt<4;rt++){
    floatx4 sv  = *(const floatx4*)&sbuf [rowBase + rt*16+q*4];
    floatx4 ssv = *(const floatx4*)&ssbuf[rowBase + rt*16+q*4];
    #pragma unroll
    for (int r=0;r<4;r++){
      float mu = sv[r]*invN;
      float rs = rsqrtf(ssv[r]*invN - mu*mu + 1e-5f);
      int row = rowBase + rt*16+q*4+r;
      float y[4];
      #pragma unroll
      for (int ct=0;ct<4;ct++)
        y[ct] = fmaxf((acc[rt][ct][r]+bias[ct]-mu)*rs*g[ct]+be[ct], 0.f);
      uint2 pk; pk.x = f2bf_pk(y[0],y[1]); pk.y = f2bf_pk(y[2],y[3]);
      *(uint2*)(act_ + row*AST + colBase + ln*4) = pk;
    }
  }
}

// =====================================================================
// fused forward: 128 rows/block, 8 waves. L1/L2 col-split (5 barriers),
// L3 + heads + output row-split per wave (barrier-free tail).
// =====================================================================
__global__ __launch_bounds__(512,2) void dqn_main(
    const float* __restrict__ state, const float* __restrict__ td,
    const int* __restrict__ et, const unsigned short* __restrict__ wq,
    const float* __restrict__ cq, float* __restrict__ out)
{
  __shared__ __align__(16) unsigned short act[TM*AST];   // 67.6 KB
  __shared__ float sstat[2][2][TM];                       // 2 KB

  const int tid=threadIdx.x, w=tid>>6, lane=tid&63, q=lane>>4, ln=lane&15;
  const int wr=w>>2, wc=w&3;
  const int rowBlk = blockIdx.x*TM;

  // ---- stage x: 4 threads/row, 25 col-pairs each, v_cvt_pk + b32 writes ----
  {
    ((float*)sstat)[tid] = 0.f;                      // zero both stat ping-pongs
    const int row = tid>>2, t = tid&3;
    const float* srow = state + (size_t)(rowBlk+row)*199;
    unsigned short* arow = act + row*AST;
    #pragma unroll
    for (int jj=0; jj<25; jj++){
      int c = (t*25+jj)*2;
      float v0 = srow[c];
      float v1 = (c==198) ? td[rowBlk+row] : srow[c+1];
      *(uint32_t*)(arow + c) = f2bf_pk(v0, v1);
    }
    if (t==0) *(uint32_t*)(arow + 200) = 0x00003F80u;   // (1.0, 0): W1 bias row
    #pragma unroll
    for (int z=0; z<3; z++)
      *(uint32_t*)(arow + 202 + t*6 + z*2) = 0u;        // zero cols 202..225
  }
  __syncthreads();                                        // B1

  floatx4 acc[4][4];
  float bias[4];
  const unsigned short* aBase12 = act + (wr*64 + ln)*AST + q*8;

  // ---- L1: x(224 incl bias row) -> h1(256). rows [64wr,..), cols [64wc,..) ----
  zeroAcc44(acc);
  runGemm44<7>(acc, wq + OFF_W1 + wc*14336, aBase12, lane);
  statsAtomic<false>(acc, cq, 0, wc*64, wr*64, sstat[0][0], sstat[0][1], ln, q, bias);
  __syncthreads();                                        // B2
  lnWrite44(acc, cq, C_G1, C_BE1, wc*64, wr*64, sstat[0][0], sstat[0][1], 1.f/256.f, act, ln, q, bias);
  __syncthreads();                                        // B3

  // ---- L2: h1(256) -> h2(256) ----
  zeroAcc44(acc);
  runGemm44<8>(acc, wq + OFF_W2 + wc*16384, aBase12, lane);
  statsAtomic<true>(acc, cq, C_B2, wc*64, wr*64, sstat[1][0], sstat[1][1], ln, q, bias);
  __syncthreads();                                        // B4
  lnWrite44(acc, cq, C_G2, C_BE2, wc*64, wr*64, sstat[1][0], sstat[1][1], 1.f/256.f, act, ln, q, bias);
  __syncthreads();                                        // B5 — last barrier

  // ================= barrier-free tail: wave w owns rows 16w..16w+15 ========
  const unsigned short* aR = act + (16*w + ln)*AST + q*8;
  int etv[4];
  #pragma unroll
  for (int r=0;r<4;r++) etv[r] = et[rowBlk + 16*w + q*4 + r];

  // ---- L3: h2(256) -> f(128), all cols in-wave ----
  {
    floatx4 a8[8];
    const floatx4 z = {0.f,0.f,0.f,0.f};
    #pragma unroll
    for (int nt=0;nt<8;nt++) a8[nt]=z;
    #pragma unroll
    for (int kc=0;kc<8;kc++){
      short8 a = *(const short8*)(aR + kc*32);
      #pragma unroll
      for (int nt=0;nt<8;nt++){
        short8 b = *(const short8*)(wq + OFF_W3 + (nt>>1)*8192 + kc*1024 + (nt&1)*512 + lane*8);
        a8[nt] = __builtin_amdgcn_mfma_f32_16x16x32_bf16(a, b, a8[nt], 0,0,0);
      }
    }
    float bi[8], g[8], be[8];
    #pragma unroll
    for (int nt=0;nt<8;nt++){
      bi[nt]=cq[C_B3+nt*16+ln]; g[nt]=cq[C_G3+nt*16+ln]; be[nt]=cq[C_BE3+nt*16+ln];
    }
    #pragma unroll
    for (int r=0;r<4;r++){
      float s=0, ss=0;
      #pragma unroll
      for (int nt=0;nt<8;nt++){ float v=a8[nt][r]+bi[nt]; s+=v; ss+=v*v; }
      #pragma unroll
      for (int d=1;d<16;d<<=1){ s+=__shfl_xor(s,d); ss+=__shfl_xor(ss,d); }
      float mu=s*(1.f/128.f), rs=rsqrtf(ss*(1.f/128.f)-mu*mu+1e-5f);
      float y[8];
      #pragma unroll
      for (int nt=0;nt<8;nt++)
        y[nt]=fmaxf((a8[nt][r]+bi[nt]-mu)*rs*g[nt]+be[nt], 0.f);
      int row = 16*w + q*4 + r;
      uint4 pk;
      pk.x=f2bf_pk(y[0],y[1]); pk.y=f2bf_pk(y[2],y[3]);
      pk.z=f2bf_pk(y[4],y[5]); pk.w=f2bf_pk(y[6],y[7]);
      *(uint4*)(act + row*AST + ln*8) = pk;     // f pack: pos p=8*ln+nt -> c=16nt+ln
    }
  }

  // ---- heads: this wave does ALL 4 heads for its 16 rows ----
  float vrow[4];
  float advsel[2][4] = {{0,0,0,0},{0,0,0,0}};
  #pragma unroll
  for (int h=0;h<4;h++){            // h==0 value head done last? order: 3 first
    int hh = (h==0)? 3 : h-1;       // value head first, then adv 0,1,2
    floatx4 hc[4];
    const floatx4 z = {0.f,0.f,0.f,0.f};
    #pragma unroll
    for (int ct=0;ct<4;ct++) hc[ct]=z;
    #pragma unroll
    for (int kc=0;kc<4;kc++){
      short8 a = *(const short8*)(aR + kc*32);
      #pragma unroll
      for (int ct=0;ct<4;ct++){
        short8 b = *(const short8*)(wq + OFF_WH + hh*8192 + kc*2048 + ct*512 + lane*8);
        hc[ct] = __builtin_amdgcn_mfma_f32_16x16x32_bf16(a, b, hc[ct], 0,0,0);
      }
    }
    const int bo = (hh<3)? C_BA1+hh*64 : C_BV1;
    const int go = (hh<3)? C_GA +hh*64 : C_GV;
    const int beo= (hh<3)? C_BEA+hh*64 : C_BEV;
    float bi[4], g[4], be[4];
    #pragma unroll
    for (int ct=0;ct<4;ct++){ bi[ct]=cq[bo+ct*16+ln]; g[ct]=cq[go+ct*16+ln]; be[ct]=cq[beo+ct*16+ln]; }
    float y[4][4];   // [ct][r]
    #pragma unroll
    for (int r=0;r<4;r++){
      float s=0, ss=0;
      #pragma unroll
      for (int ct=0;ct<4;ct++){ float v=hc[ct][r]+bi[ct]; y[ct][r]=v; s+=v; ss+=v*v; }
      #pragma unroll
      for (int d=1;d<16;d<<=1){ s+=__shfl_xor(s,d); ss+=__shfl_xor(ss,d); }
      float mu=s*(1.f/64.f), rs=rsqrtf(ss*(1.f/64.f)-mu*mu+1e-5f);
      #pragma unroll
      for (int ct=0;ct<4;ct++)
        y[ct][r]=fmaxf((y[ct][r]-mu)*rs*g[ct]+be[ct], 0.f);
    }
    if (hh==3){
      // value: v = y . Wv2 + bv2
      float wv[4];
      #pragma unroll
      for (int ct=0;ct<4;ct++) wv[ct]=cq[C_WV2+ct*16+ln];
      float bv2v = cq[C_BV2];
      #pragma unroll
      for (int r=0;r<4;r++){
        float dd=0;
        #pragma unroll
        for (int ct=0;ct<4;ct++) dd+=y[ct][r]*wv[ct];
        #pragma unroll
        for (int d=1;d<16;d<<=1) dd+=__shfl_xor(dd,d);
        vrow[r]=dd+bv2v;
      }
    } else {
      // adv head hh: pack ha into wave-local act cols 128..191, a2 GEMM, select
      #pragma unroll
      for (int r=0;r<4;r++){
        int row = 16*w + q*4 + r;
        uint2 pk; pk.x=f2bf_pk(y[0][r],y[1][r]); pk.y=f2bf_pk(y[2][r],y[3][r]);
        *(uint2*)(act + row*AST + 128 + ln*4) = pk;   // p=4*ln+ct -> c=16ct+ln
      }
      floatx4 a2c[2];
      const floatx4 z2 = {0.f,0.f,0.f,0.f};
      a2c[0]=z2; a2c[1]=z2;
      #pragma unroll
      for (int kc=0;kc<2;kc++){
        short8 a = *(const short8*)(act + (16*w+ln)*AST + 128 + q*8 + kc*32);
        #pragma unroll
        for (int ct=0;ct<2;ct++){
          short8 b = *(const short8*)(wq + OFF_WA2 + hh*2048 + kc*1024 + ct*512 + lane*8);
          a2c[ct] = __builtin_amdgcn_mfma_f32_16x16x32_bf16(a, b, a2c[ct], 0,0,0);
        }
      }
      #pragma unroll
      for (int ct=0;ct<2;ct++){
        float b2v = cq[C_BA2 + hh*32 + ct*16 + ln];
        #pragma unroll
        for (int r=0;r<4;r++){
          float av = a2c[ct][r] + b2v;
          if (etv[r]==hh) advsel[ct][r] = av;
        }
      }
    }
  }

  // ---- output: out = v + adv - mean(adv), direct global stores ----
  #pragma unroll
  for (int r=0;r<4;r++){
    float sm = advsel[0][r] + advsel[1][r];
    #pragma unroll
    for (int d=1;d<16;d<<=1) sm += __shfl_xor(sm,d);
    float m = sm*(1.f/32.f);
    int row = rowBlk + 16*w + q*4 + r;
    float* op = out + (size_t)row*32 + ln;
    op[0]  = vrow[r] + advsel[0][r] - m;
    op[16] = vrow[r] + advsel[1][r] - m;
  }
}

// =====================================================================
extern "C" void kernel_launch(void* const* d_in, const int* in_sizes, int n_in,
                              void* d_out, int out_size, void* d_ws, size_t ws_size,
                              hipStream_t stream)
{
  Ptrs p;
  p.state=(const float*)d_in[0];  p.td =(const float*)d_in[1];
  p.W1 =(const float*)d_in[2];  p.b1 =(const float*)d_in[3];  p.g1 =(const float*)d_in[4];  p.be1=(const float*)d_in[5];
  p.W2 =(const float*)d_in[6];  p.b2 =(const float*)d_in[7];  p.g2 =(const float*)d_in[8];  p.be2=(const float*)d_in[9];
  p.W3 =(const float*)d_in[10]; p.b3 =(const float*)d_in[11]; p.g3 =(const float*)d_in[12]; p.be3=(const float*)d_in[13];
  p.Wv1=(const float*)d_in[14]; p.bv1=(const float*)d_in[15]; p.gv =(const float*)d_in[16]; p.bev=(const float*)d_in[17];
  p.Wv2=(const float*)d_in[18]; p.bv2=(const float*)d_in[19];
  p.Wa1=(const float*)d_in[20]; p.ba1=(const float*)d_in[21]; p.ga =(const float*)d_in[22]; p.bea=(const float*)d_in[23];
  p.Wa2=(const float*)d_in[24]; p.ba2=(const float*)d_in[25];
  p.et =(const int*)d_in[26];

  unsigned short* wq = (unsigned short*)d_ws;
  float* cq = (float*)((char*)d_ws + (size_t)NWQ*2);

  const int prepN = NWQ + NCONST;
  hipLaunchKernelGGL(prep_kernel, dim3((prepN+255)/256), dim3(256), 0, stream, p, wq, cq);
  hipLaunchKernelGGL(dqn_main, dim3(NB/TM), dim3(512), 0, stream,
                     p.state, p.td, p.et, (const unsigned short*)wq, (const float*)cq, (float*)d_out);
}